// Round 12
// baseline (25.036 us; speedup 1.0000x reference)
//
#include <hip/hip_runtime.h>
#include <stdint.h>

#define CN 144
#define VN 576
#define BN 1024
#define NITER 3
#define NQ   8       // quads per check row: RCAP=32 slots (max row weight <=32, proven R9-R11)
#define CCAP 8       // column-weight capacity (actual 4, rare 5)
#define TPB 192      // 3 waves; 576/192 = exactly 3 columns per thread

// ws layout (ints):
#define WS_RCTR 0      // [0,144)   monotonic slot counters — NEVER reset; slot = old & 31.
                       // Per call each advances by rl(c) <= 32 -> slots form a contiguous
                       // run mod 32 -> distinct within a call. Slot permutation across
                       // calls is output-invariant: min/min2/sign are commutative and the
                       // ab==m1 exclusion is order-free; colsum order = ascending c (ballot).
#define WS_CCNT 144    // [144,720)  per-column edge count
#define WS_CSC  720    // [720, 720+CCAP*VN) slot-major [j][v] = edge id

// edge id for (row-slot l, check c), quad layout: float index
// ((l>>2)*CN + c)*4 + (l&3) -> lane-consecutive float4 per (l>>2, c)
__device__ __forceinline__ int edge_id(int l, int c) {
    return (((l >> 2) * CN + c) << 2) | (l & 3);
}

// ---- single build kernel: one wave per column, direct H reads (L2-hot),
//      atomic slot claim per check, ascending-c CSC via ballot ----
__global__ __launch_bounds__(64) void build_csc(const float* __restrict__ H,
                                                int* __restrict__ ws) {
    const int v = blockIdx.x;          // 576 blocks
    const int lane = threadIdx.x;      // 64
    int cnt = 0;
    for (int ch = 0; ch < 3; ++ch) {
        const int c = ch * 64 + lane;
        const bool set = (c < CN) && (H[c * VN + v] > 0.5f);
        const unsigned long long mask = __ballot(set);
        const int off = cnt + (int)__popcll(mask & ((1ULL << lane) - 1ULL));
        if (set && off < CCAP) {
            const unsigned old = atomicAdd((unsigned*)(ws + WS_RCTR + c), 1u);
            ws[WS_CSC + off * VN + v] = edge_id((int)(old & 31u), c);
        }
        cnt += (int)__popcll(mask);
    }
    if (cnt > CCAP) cnt = CCAP;
    if (lane == 0) ws[WS_CCNT + v] = cnt;
    if (lane >= cnt && lane < CCAP) ws[WS_CSC + lane * VN + v] = 0;  // defined, unused
}

// ---- decode: one block per batch item; R11 body, fixed 8-quad Pass A,
//      INF-pad-preserving writeback ----
__global__ __launch_bounds__(TPB) void ldpc_decode(const float* __restrict__ r,
                                                   const float* __restrict__ alpha,
                                                   const int* __restrict__ ws,
                                                   float* __restrict__ out) {
    __shared__ float4 M4[NQ * CN];     // 18.4 KB
    float* const Mf = reinterpret_cast<float*>(M4);

    const int b = blockIdx.x;
    const int t = threadIdx.x;
    const float a_[NITER] = { alpha[0], alpha[1], alpha[2] };

    // per-thread columns v = t + q*TPB
    int ent4[3][4], entX[3][4];
    int cnt[3];
    float rv[3];
    #pragma unroll
    for (int q = 0; q < 3; ++q) {
        const int v = t + q * TPB;
        rv[q]  = r[b * VN + v];
        cnt[q] = ws[WS_CCNT + v];
        #pragma unroll
        for (int j = 0; j < 4; ++j) ent4[q][j] = ws[WS_CSC + j * VN + v];
    }
    const int any_hi = __syncthreads_or((cnt[0] > 4) | (cnt[1] > 4) | (cnt[2] > 4));
    if (any_hi) {
        #pragma unroll
        for (int q = 0; q < 3; ++q)
            #pragma unroll
            for (int j = 0; j < 4; ++j) entX[q][j] = ws[WS_CSC + (4 + j) * VN + t + q * TPB];
    }

    // fill ALL slots with +INF (non-edge slots stay INF: sign +1, never a min)
    const float4 inf4 = make_float4(INFINITY, INFINITY, INFINITY, INFINITY);
    for (int i = t; i < NQ * CN; i += TPB) M4[i] = inf4;
    __syncthreads();
    // M init = r on real edges
    #pragma unroll
    for (int q = 0; q < 3; ++q) {
        #pragma unroll
        for (int j = 0; j < 4; ++j) if (j < cnt[q]) Mf[ent4[q][j]] = rv[q];
    }
    if (any_hi) {
        #pragma unroll
        for (int q = 0; q < 3; ++q) {
            #pragma unroll
            for (int j = 0; j < 4; ++j) if (4 + j < cnt[q]) Mf[entX[q][j]] = rv[q];
        }
    }
    __syncthreads();

    #pragma unroll
    for (int it = 0; it < NITER; ++it) {
        const float a = a_[it];

        // Pass A: fixed 8-quad 5-op two-smallest scan (register-cached), then
        // E writeback in place; INF pads preserved (they must survive to next scan).
        if (t < CN) {
            float4 mq[NQ];
            uint32_t m1 = 0x7fffffffu, m2 = 0x7fffffffu, sg = 0u;
            #pragma unroll
            for (int q4 = 0; q4 < NQ; ++q4) {
                mq[q4] = M4[q4 * CN + t];
                const uint32_t* mu = reinterpret_cast<const uint32_t*>(&mq[q4]);
                #pragma unroll
                for (int j = 0; j < 4; ++j) {
                    const uint32_t mb = mu[j];
                    const uint32_t ab = mb & 0x7fffffffu;  // INF pads never win
                    sg ^= mb;
                    const uint32_t hi = (ab > m1) ? ab : m1;
                    m1 = (ab < m1) ? ab : m1;
                    m2 = (hi < m2) ? hi : m2;
                }
            }
            sg &= 0x80000000u;                             // pads are +INF: sign +1
            const uint32_t p1b = __float_as_uint(a * __uint_as_float(m1)) ^ sg;
            const uint32_t p2b = __float_as_uint(a * __uint_as_float(m2)) ^ sg;
            // exclusion by ab==m1: unique min -> exact argmin; ties -> p1b==p2b
            #pragma unroll
            for (int q4 = 0; q4 < NQ; ++q4) {
                const uint32_t* mu = reinterpret_cast<const uint32_t*>(&mq[q4]);
                float4 ev;
                uint32_t* eu = reinterpret_cast<uint32_t*>(&ev);
                #pragma unroll
                for (int j = 0; j < 4; ++j) {
                    const uint32_t mb = mu[j];
                    const uint32_t ab = mb & 0x7fffffffu;
                    const uint32_t e  = ((ab == m1) ? p2b : p1b) ^ (mb & 0x80000000u);
                    eu[j] = (ab == 0x7f800000u) ? mb : e;  // preserve INF pads
                }
                M4[q4 * CN + t] = ev;
            }
        }
        __syncthreads();

        // Pass B: per-column gather of E (ascending c), col-sum, fused M update
        #pragma unroll
        for (int q = 0; q < 3; ++q) {
            float E4[4], EX[4];
            float col = 0.0f;
            #pragma unroll
            for (int j = 0; j < 4; ++j) {
                E4[j] = (j < cnt[q]) ? Mf[ent4[q][j]] : 0.0f;
                col += E4[j];
            }
            if (any_hi) {
                #pragma unroll
                for (int j = 0; j < 4; ++j) {
                    EX[j] = (4 + j < cnt[q]) ? Mf[entX[q][j]] : 0.0f;
                    col += EX[j];
                }
            }
            if (it == NITER - 1) {
                out[b * VN + t + q * TPB] = rv[q] + col;
            } else {
                const float mb = col + rv[q];
                #pragma unroll
                for (int j = 0; j < 4; ++j) if (j < cnt[q]) Mf[ent4[q][j]] = mb - E4[j];
                if (any_hi) {
                    #pragma unroll
                    for (int j = 0; j < 4; ++j) if (4 + j < cnt[q]) Mf[entX[q][j]] = mb - EX[j];
                }
            }
        }
        if (it < NITER - 1) __syncthreads();
    }
}

extern "C" void kernel_launch(void* const* d_in, const int* in_sizes, int n_in,
                              void* d_out, int out_size, void* d_ws, size_t ws_size,
                              hipStream_t stream) {
    const float* r     = (const float*)d_in[0];
    const float* alpha = (const float*)d_in[1];
    const float* H     = (const float*)d_in[2];
    float* out = (float*)d_out;
    int* ws    = (int*)d_ws;

    build_csc<<<VN, 64, 0, stream>>>(H, ws);
    ldpc_decode<<<BN, TPB, 0, stream>>>(r, alpha, ws, out);
}